// Round 8
// baseline (2069.988 us; speedup 1.0000x reference)
//
#include <hip/hip_runtime.h>

// Problem constants
#define NPIX 8192      // B*H*W
#define EDIM 256
#define KCB  8192
#define OUT_ZQ   0
#define OUT_DIFF 2097152
#define OUT_IND  2097153

// ws layout (bytes) — total 266,240 <= proven 565,248
#define WS_A     0         // 8192 f32
#define WS_N     32768     // 8192 f32
#define WS_PVAL  65536     // 8192*4 f32 = 128 KB
#define WS_PIDX  196608    // 8192*4 u16 = 64 KB
#define WS_PART  262144    // 1024 f32

// ---------------------------------------------------------------- z_e: bit-exact np.einsum replica
__global__ __launch_bounds__(256) void k_ze_np(const float* __restrict__ z,
                                               const float* __restrict__ pw,
                                               const float* __restrict__ pb,
                                               float* __restrict__ ze) {
    __shared__ float lz[32][16];
    __shared__ float lw[256][33];
    const int t   = threadIdx.x;
    const int b   = blockIdx.x >> 6;
    const int hw0 = (blockIdx.x & 63) * 16;

    float acc[16];
#pragma unroll
    for (int p = 0; p < 16; ++p) acc[p] = 0.0f;

    for (int cc = 0; cc < 256; cc += 32) {
        float4 wv[8];
        const float4* wsrc = reinterpret_cast<const float4*>(pw + (size_t)t * 256 + cc);
#pragma unroll
        for (int i = 0; i < 8; ++i) wv[i] = wsrc[i];
        float zv[2];
#pragma unroll
        for (int i = 0; i < 2; ++i) {
            const int f = t + i * 256;           // 0..511
            zv[i] = z[(size_t)(b * 256 + cc + (f >> 4)) * 1024 + hw0 + (f & 15)];
        }
        __syncthreads();   // previous chunk's reads complete
#pragma unroll
        for (int i = 0; i < 8; ++i) {
            lw[t][i * 4 + 0] = wv[i].x;
            lw[t][i * 4 + 1] = wv[i].y;
            lw[t][i * 4 + 2] = wv[i].z;
            lw[t][i * 4 + 3] = wv[i].w;
        }
#pragma unroll
        for (int i = 0; i < 2; ++i) {
            const int f = t + i * 256;
            lz[f >> 4][f & 15] = zv[i];
        }
        __syncthreads();
#pragma unroll 8
        for (int cl = 0; cl < 32; ++cl) {
            const float wl = lw[t][cl];
#pragma unroll
            for (int p = 0; p < 16; ++p)
                acc[p] = __fadd_rn(acc[p], __fmul_rn(lz[cl][p], wl));
        }
    }
    const float bb = pb[t];
#pragma unroll
    for (int p = 0; p < 16; ++p)
        ze[(size_t)(b * 1024 + hw0 + p) * 256 + t] = __fadd_rn(acc[p], bb);
}

// ---------------------------------------------------------------- np.sum(x*x, axis=1) pairwise replica (n=256)
__global__ __launch_bounds__(256) void k_rowstats(const float* __restrict__ ze,
                                                  const float* __restrict__ embed,
                                                  float* __restrict__ A,
                                                  float* __restrict__ Nf) {
    const int gid = blockIdx.x * 256 + threadIdx.x;     // 0..16383
    const float* row = (gid < 8192) ? (ze + (size_t)gid * 256)
                                    : (embed + (size_t)(gid - 8192) * 256);
    float blk[2];
#pragma unroll
    for (int half = 0; half < 2; ++half) {
        const float4* r4 = reinterpret_cast<const float4*>(row + half * 128);
        float r[8];
#pragma unroll
        for (int i = 0; i < 16; ++i) {
            const float4 a = r4[i * 2], b = r4[i * 2 + 1];
            const float s[8] = {__fmul_rn(a.x, a.x), __fmul_rn(a.y, a.y),
                                __fmul_rn(a.z, a.z), __fmul_rn(a.w, a.w),
                                __fmul_rn(b.x, b.x), __fmul_rn(b.y, b.y),
                                __fmul_rn(b.z, b.z), __fmul_rn(b.w, b.w)};
            if (i == 0) {
#pragma unroll
                for (int j = 0; j < 8; ++j) r[j] = s[j];
            } else {
#pragma unroll
                for (int j = 0; j < 8; ++j) r[j] = __fadd_rn(r[j], s[j]);
            }
        }
        blk[half] = __fadd_rn(__fadd_rn(__fadd_rn(r[0], r[1]), __fadd_rn(r[2], r[3])),
                              __fadd_rn(__fadd_rn(r[4], r[5]), __fadd_rn(r[6], r[7])));
    }
    const float res = __fadd_rn(blk[0], blk[1]);
    if (gid < 8192) A[gid] = res;
    else            Nf[gid - 8192] = res;
}

// ---------------------------------------------------------------- dist replica + argmin: lane<->px, e from global
// grid 512 = 128 px-tiles(64 px) x 4 k-splits(2048 k). 4 waves split k (512 each).
// Per lane: 1 px, kc-chunks of 16 k with acc[16]; e loads wave-uniform (L1 broadcast);
// z from LDS [64][260] (pad-65-word rows -> balanced banks), 1 b128 per 4c reused by 16 k.
// Chain per (px,k): c-ascending single fmaf on 2*z_e  — bit-identical to rounds 5-7.
__global__ __launch_bounds__(256, 2) void k_dist_np(const float* __restrict__ ze,
                                                    const float* __restrict__ embed,
                                                    const float* __restrict__ A,
                                                    const float* __restrict__ Nf,
                                                    float* __restrict__ pval,
                                                    unsigned short* __restrict__ pidx) {
    __shared__ float z2l[64][260];
    __shared__ float red[64][4][2];
    const int t    = threadIdx.x;
    const int ks   = blockIdx.x & 3;
    const int pt   = blockIdx.x >> 2;
    const int pix0 = pt * 64;
    const int k0   = ks * 2048;
    const int w    = t >> 6;        // wave id
    const int lane = t & 63;        // = px within tile

    // stage 2*z_e (exact prescale) for 64 px x 256 c
    {
        const int px = t >> 2, cq = (t & 3) * 64;
        const float4* src = reinterpret_cast<const float4*>(ze + (size_t)(pix0 + px) * 256 + cq);
#pragma unroll
        for (int m = 0; m < 16; ++m) {
            const float4 v = src[m];
            float* dst = &z2l[px][cq + m * 4];
            dst[0] = __fmul_rn(2.0f, v.x);
            dst[1] = __fmul_rn(2.0f, v.y);
            dst[2] = __fmul_rn(2.0f, v.z);
            dst[3] = __fmul_rn(2.0f, v.w);
        }
    }
    __syncthreads();

    const float Ai = A[pix0 + lane];
    const int   kw = k0 + w * 512;

    float best = 3.402823466e+38f;
    int   bidx = 0x7fffffff;

    for (int kc = 0; kc < 512; kc += 16) {
        const int kbase = kw + kc;
        float acc[16];
#pragma unroll
        for (int kk = 0; kk < 16; ++kk) acc[kk] = 0.0f;

#pragma unroll 2
        for (int c4 = 0; c4 < 64; ++c4) {
            float4 ev[16];
#pragma unroll
            for (int kk = 0; kk < 16; ++kk)
                ev[kk] = reinterpret_cast<const float4*>(embed + (size_t)(kbase + kk) * 256)[c4];
            const float4 zq = *reinterpret_cast<const float4*>(&z2l[lane][c4 * 4]);
#pragma unroll
            for (int kk = 0; kk < 16; ++kk) {   // c ascending within each (px,k)
                acc[kk] = fmaf(zq.x, ev[kk].x, acc[kk]);
                acc[kk] = fmaf(zq.y, ev[kk].y, acc[kk]);
                acc[kk] = fmaf(zq.z, ev[kk].z, acc[kk]);
                acc[kk] = fmaf(zq.w, ev[kk].w, acc[kk]);
            }
        }
        // scores; kk ascending == k ascending -> strict < keeps first occurrence
#pragma unroll
        for (int kk = 0; kk < 16; ++kk) {
            const float v = __fadd_rn(__fsub_rn(Ai, acc[kk]), Nf[kbase + kk]);
            if (v < best) { best = v; bidx = kbase + kk; }
        }
    }
    red[lane][w][0] = best;
    red[lane][w][1] = __int_as_float(bidx);
    __syncthreads();
    if (t < 64) {
        float bv = 3.402823466e+38f;
        int   bk = 0x7fffffff;
#pragma unroll
        for (int q = 0; q < 4; ++q) {    // q ascending == k ascending
            const float v  = red[t][q][0];
            const int   ki = __float_as_int(red[t][q][1]);
            if (v < bv || (v == bv && ki < bk)) { bv = v; bk = ki; }
        }
        pval[(size_t)(pix0 + t) * 4 + ks] = bv;
        pidx[(size_t)(pix0 + t) * 4 + ks] = (unsigned short)bk;
    }
}

// ---------------------------------------------------------------- combine 4 k-splits (lexicographic)
__global__ __launch_bounds__(256) void k_combine(const float* __restrict__ pval,
                                                 const unsigned short* __restrict__ pidx,
                                                 float* __restrict__ out_ind) {
    const int n = blockIdx.x * 256 + threadIdx.x;
    float bv = 3.402823466e+38f;
    int   bk = 0x7fffffff;
#pragma unroll
    for (int s = 0; s < 4; ++s) {        // ks ascending == k ascending
        const float v  = pval[(size_t)n * 4 + s];
        const int   ki = pidx[(size_t)n * 4 + s];
        if (v < bv || (v == bv && ki < bk)) { bv = v; bk = ki; }
    }
    out_ind[n] = (float)bk;
}

// ---------------------------------------------------------------- gather z_q (overwrite z_e) + partial MSE (f64)
__global__ __launch_bounds__(256) void k_gather(const float* __restrict__ embed,
                                                float* __restrict__ out,
                                                const float* __restrict__ out_ind,
                                                float* __restrict__ part) {
    __shared__ double wsum[4];
    const int t = threadIdx.x;
    const int g = t >> 5, l = t & 31;
    const int n = blockIdx.x * 8 + g;
    const int idx = (int)(out_ind[n] + 0.5f);
    const float4* ev4 = reinterpret_cast<const float4*>(embed + (size_t)idx * EDIM);
    float4* zp = reinterpret_cast<float4*>(out + (size_t)n * EDIM);
    double s = 0.0;
#pragma unroll
    for (int r = 0; r < 2; ++r) {
        const float4 ev = ev4[l + r * 32];
        const float4 zv = zp[l + r * 32];
        const double dx = (double)ev.x - zv.x, dy = (double)ev.y - zv.y;
        const double dz = (double)ev.z - zv.z, dw = (double)ev.w - zv.w;
        s += dx * dx + dy * dy + dz * dz + dw * dw;
        zp[l + r * 32] = ev;             // z_q_st == z_q numerically
    }
    for (int off = 32; off; off >>= 1) s += __shfl_down(s, off, 64);
    const int wid = t >> 6, lane = t & 63;
    if (lane == 0) wsum[wid] = s;
    __syncthreads();
    if (t == 0) part[blockIdx.x] = (float)(wsum[0] + wsum[1] + wsum[2] + wsum[3]);
}

// ---------------------------------------------------------------- final diff reduction (f64)
__global__ __launch_bounds__(256) void k_final(const float* __restrict__ part,
                                               float* __restrict__ out_diff) {
    __shared__ double wsum[4];
    double s = 0.0;
#pragma unroll
    for (int i = 0; i < 4; ++i) s += (double)part[threadIdx.x + i * 256];
    for (int off = 32; off; off >>= 1) s += __shfl_down(s, off, 64);
    const int wid = threadIdx.x >> 6, lane = threadIdx.x & 63;
    if (lane == 0) wsum[wid] = s;
    __syncthreads();
    if (threadIdx.x == 0)
        out_diff[0] = (float)(2.0 * (wsum[0] + wsum[1] + wsum[2] + wsum[3]) / 2097152.0);
}

extern "C" void kernel_launch(void* const* d_in, const int* in_sizes, int n_in,
                              void* d_out, int out_size, void* d_ws, size_t ws_size,
                              hipStream_t stream) {
    const float* z     = (const float*)d_in[0];
    const float* pw    = (const float*)d_in[1];
    const float* pb    = (const float*)d_in[2];
    const float* embed = (const float*)d_in[3];
    float* out = (float*)d_out;
    char*  ws  = (char*)d_ws;

    float*          A    = (float*)(ws + WS_A);
    float*          Nf   = (float*)(ws + WS_N);
    float*          pval = (float*)(ws + WS_PVAL);
    unsigned short* pidx = (unsigned short*)(ws + WS_PIDX);
    float*          part = (float*)(ws + WS_PART);

    float* ze       = out + OUT_ZQ;      // z_e lives in z_q slot, overwritten by gather
    float* out_diff = out + OUT_DIFF;
    float* out_ind  = out + OUT_IND;

    k_ze_np   <<<512,  256, 0, stream>>>(z, pw, pb, ze);
    k_rowstats<<<64,   256, 0, stream>>>(ze, embed, A, Nf);
    k_dist_np <<<512,  256, 0, stream>>>(ze, embed, A, Nf, pval, pidx);
    k_combine <<<32,   256, 0, stream>>>(pval, pidx, out_ind);
    k_gather  <<<1024, 256, 0, stream>>>(embed, out + OUT_ZQ, out_ind, part);
    k_final   <<<1,    256, 0, stream>>>(part, out_diff);
}

// Round 9
// 627.697 us; speedup vs baseline: 3.2978x; 3.2978x over previous
//
#include <hip/hip_runtime.h>

// Problem constants
#define NPIX 8192      // B*H*W
#define EDIM 256
#define KCB  8192
#define OUT_ZQ   0
#define OUT_DIFF 2097152
#define OUT_IND  2097153

// ws layout (bytes) — total 135,168 <= proven 565,248
#define WS_AMIN 0          // 8192 u64 packed (key<<32 | idx)
#define WS_A    65536      // 8192 f32
#define WS_N    98304      // 8192 f32
#define WS_PART 131072     // 1024 f32

// ---------------------------------------------------------------- init packed argmin array
__global__ __launch_bounds__(256) void k_init(unsigned long long* __restrict__ amin) {
    amin[blockIdx.x * 256 + threadIdx.x] = ~0ULL;
}

// ---------------------------------------------------------------- z_e: bit-exact np.einsum replica
__global__ __launch_bounds__(256) void k_ze_np(const float* __restrict__ z,
                                               const float* __restrict__ pw,
                                               const float* __restrict__ pb,
                                               float* __restrict__ ze) {
    __shared__ float lz[32][16];
    __shared__ float lw[256][33];
    const int t   = threadIdx.x;
    const int b   = blockIdx.x >> 6;
    const int hw0 = (blockIdx.x & 63) * 16;

    float acc[16];
#pragma unroll
    for (int p = 0; p < 16; ++p) acc[p] = 0.0f;

    for (int cc = 0; cc < 256; cc += 32) {
        float4 wv[8];
        const float4* wsrc = reinterpret_cast<const float4*>(pw + (size_t)t * 256 + cc);
#pragma unroll
        for (int i = 0; i < 8; ++i) wv[i] = wsrc[i];
        float zv[2];
#pragma unroll
        for (int i = 0; i < 2; ++i) {
            const int f = t + i * 256;           // 0..511
            zv[i] = z[(size_t)(b * 256 + cc + (f >> 4)) * 1024 + hw0 + (f & 15)];
        }
        __syncthreads();   // previous chunk's reads complete
#pragma unroll
        for (int i = 0; i < 8; ++i) {
            lw[t][i * 4 + 0] = wv[i].x;
            lw[t][i * 4 + 1] = wv[i].y;
            lw[t][i * 4 + 2] = wv[i].z;
            lw[t][i * 4 + 3] = wv[i].w;
        }
#pragma unroll
        for (int i = 0; i < 2; ++i) {
            const int f = t + i * 256;
            lz[f >> 4][f & 15] = zv[i];
        }
        __syncthreads();
#pragma unroll 8
        for (int cl = 0; cl < 32; ++cl) {
            const float wl = lw[t][cl];
#pragma unroll
            for (int p = 0; p < 16; ++p)
                acc[p] = __fadd_rn(acc[p], __fmul_rn(lz[cl][p], wl));
        }
    }
    const float bb = pb[t];
#pragma unroll
    for (int p = 0; p < 16; ++p)
        ze[(size_t)(b * 1024 + hw0 + p) * 256 + t] = __fadd_rn(acc[p], bb);
}

// ---------------------------------------------------------------- np.sum(x*x, axis=1) pairwise replica (n=256)
__global__ __launch_bounds__(256) void k_rowstats(const float* __restrict__ ze,
                                                  const float* __restrict__ embed,
                                                  float* __restrict__ A,
                                                  float* __restrict__ Nf) {
    const int gid = blockIdx.x * 256 + threadIdx.x;     // 0..16383
    const float* row = (gid < 8192) ? (ze + (size_t)gid * 256)
                                    : (embed + (size_t)(gid - 8192) * 256);
    float blk[2];
#pragma unroll
    for (int half = 0; half < 2; ++half) {
        const float4* r4 = reinterpret_cast<const float4*>(row + half * 128);
        float r[8];
#pragma unroll
        for (int i = 0; i < 16; ++i) {
            const float4 a = r4[i * 2], b = r4[i * 2 + 1];
            const float s[8] = {__fmul_rn(a.x, a.x), __fmul_rn(a.y, a.y),
                                __fmul_rn(a.z, a.z), __fmul_rn(a.w, a.w),
                                __fmul_rn(b.x, b.x), __fmul_rn(b.y, b.y),
                                __fmul_rn(b.z, b.z), __fmul_rn(b.w, b.w)};
            if (i == 0) {
#pragma unroll
                for (int j = 0; j < 8; ++j) r[j] = s[j];
            } else {
#pragma unroll
                for (int j = 0; j < 8; ++j) r[j] = __fadd_rn(r[j], s[j]);
            }
        }
        blk[half] = __fadd_rn(__fadd_rn(__fadd_rn(r[0], r[1]), __fadd_rn(r[2], r[3])),
                              __fadd_rn(__fadd_rn(r[4], r[5]), __fadd_rn(r[6], r[7])));
    }
    const float res = __fadd_rn(blk[0], blk[1]);
    if (gid < 8192) A[gid] = res;
    else            Nf[gid - 8192] = res;
}

// ---------------------------------------------------------------- dist replica + argmin, 16x16 register tile
// grid 512 = 32 px-tiles(256 px) x 16 k-splits(512 k). 256 thr = 16 tp x 16 tk.
// thread: 16 px (px = (q*16+tp)*4+m) x 16 k (k = kbase + s*4+r). chunks of 256 k, cc passes of 32 c.
// LDS: le[c32][k256] 32KB + z2[c32][px256] 32KB (holds 2*z_e, exact prescale). 2 blocks/CU.
// Per c: 4+4 ds_read_b128 per 512 VALU-cyc -> LDS and VALU balanced (~0.5 B/FMA).
// Chain per (px,k): c-ascending single fmaf on 2*z_e — bit-identical to rounds 5-7.
// Cross-block argmin: packed u64 atomicMin (order-preserving key<<32 | k) — deterministic, np ties.
__global__ __launch_bounds__(256, 1) void k_dist_np(const float* __restrict__ ze,
                                                    const float* __restrict__ embed,
                                                    const float* __restrict__ A,
                                                    const float* __restrict__ Nf,
                                                    unsigned long long* __restrict__ amin) {
    __shared__ __align__(16) char smem[65536];
    float (*le)[256] = reinterpret_cast<float (*)[256]>(smem);            // [c32][k256]
    float (*z2)[256] = reinterpret_cast<float (*)[256]>(smem + 32768);    // [c32][px256]
    unsigned long long* red = reinterpret_cast<unsigned long long*>(smem); // overlay [256][17]

    const int t    = threadIdx.x;
    const int ks   = blockIdx.x & 15;
    const int pt   = blockIdx.x >> 4;
    const int pix0 = pt * 256;
    const int k0   = ks * 512;
    const int tp   = t & 15, tk = t >> 4;

    float best[16];
    int   bidx[16];
#pragma unroll
    for (int i = 0; i < 16; ++i) { best[i] = 3.402823466e+38f; bidx[i] = 0x7fffffff; }

    float Ai[16];
#pragma unroll
    for (int q = 0; q < 4; ++q)
#pragma unroll
        for (int m = 0; m < 4; ++m)
            Ai[q * 4 + m] = A[pix0 + (q * 16 + tp) * 4 + m];

    for (int kc = 0; kc < 512; kc += 256) {
        float acc[16][16];
#pragma unroll
        for (int i = 0; i < 16; ++i)
#pragma unroll
            for (int j = 0; j < 16; ++j) acc[i][j] = 0.0f;

        const int kbase = k0 + kc + tk * 16;

        for (int cc = 0; cc < 256; cc += 32) {
            // prefetch: embed row k0+kc+t (32 c) and ze row pix0+t (32 c)
            float4 se[8], sz[8];
            const float4* esrc = reinterpret_cast<const float4*>(
                embed + (size_t)(k0 + kc + t) * 256 + cc);
#pragma unroll
            for (int m = 0; m < 8; ++m) se[m] = esrc[m];
            const float4* zsrc = reinterpret_cast<const float4*>(
                ze + (size_t)(pix0 + t) * 256 + cc);
#pragma unroll
            for (int m = 0; m < 8; ++m) sz[m] = zsrc[m];
            __syncthreads();   // prior inner-loop reads complete
#pragma unroll
            for (int m = 0; m < 8; ++m) {
                le[m * 4 + 0][t] = se[m].x;
                le[m * 4 + 1][t] = se[m].y;
                le[m * 4 + 2][t] = se[m].z;
                le[m * 4 + 3][t] = se[m].w;
            }
#pragma unroll
            for (int m = 0; m < 8; ++m) {
                z2[m * 4 + 0][t] = __fmul_rn(2.0f, sz[m].x);   // exact prescale
                z2[m * 4 + 1][t] = __fmul_rn(2.0f, sz[m].y);
                z2[m * 4 + 2][t] = __fmul_rn(2.0f, sz[m].z);
                z2[m * 4 + 3][t] = __fmul_rn(2.0f, sz[m].w);
            }
            __syncthreads();
#pragma unroll 2
            for (int c = 0; c < 32; ++c) {
                float4 ev[4], zq[4];
#pragma unroll
                for (int s = 0; s < 4; ++s)
                    ev[s] = *reinterpret_cast<const float4*>(&le[c][tk * 16 + s * 4]);
#pragma unroll
                for (int q = 0; q < 4; ++q)
                    zq[q] = *reinterpret_cast<const float4*>(&z2[c][(q * 16 + tp) * 4]);
#define FMA16(i, zv)                                                       \
    acc[i][0]  = fmaf(zv, ev[0].x, acc[i][0]);                             \
    acc[i][1]  = fmaf(zv, ev[0].y, acc[i][1]);                             \
    acc[i][2]  = fmaf(zv, ev[0].z, acc[i][2]);                             \
    acc[i][3]  = fmaf(zv, ev[0].w, acc[i][3]);                             \
    acc[i][4]  = fmaf(zv, ev[1].x, acc[i][4]);                             \
    acc[i][5]  = fmaf(zv, ev[1].y, acc[i][5]);                             \
    acc[i][6]  = fmaf(zv, ev[1].z, acc[i][6]);                             \
    acc[i][7]  = fmaf(zv, ev[1].w, acc[i][7]);                             \
    acc[i][8]  = fmaf(zv, ev[2].x, acc[i][8]);                             \
    acc[i][9]  = fmaf(zv, ev[2].y, acc[i][9]);                             \
    acc[i][10] = fmaf(zv, ev[2].z, acc[i][10]);                            \
    acc[i][11] = fmaf(zv, ev[2].w, acc[i][11]);                            \
    acc[i][12] = fmaf(zv, ev[3].x, acc[i][12]);                            \
    acc[i][13] = fmaf(zv, ev[3].y, acc[i][13]);                            \
    acc[i][14] = fmaf(zv, ev[3].z, acc[i][14]);                            \
    acc[i][15] = fmaf(zv, ev[3].w, acc[i][15]);
#pragma unroll
                for (int q = 0; q < 4; ++q) {
                    FMA16(q * 4 + 0, zq[q].x)
                    FMA16(q * 4 + 1, zq[q].y)
                    FMA16(q * 4 + 2, zq[q].z)
                    FMA16(q * 4 + 3, zq[q].w)
                }
#undef FMA16
            }
        }
        // scores; thread-local k ascending (kc asc, j asc) -> strict < keeps first occurrence
        const float4 n0 = *reinterpret_cast<const float4*>(&Nf[kbase]);
        const float4 n1 = *reinterpret_cast<const float4*>(&Nf[kbase + 4]);
        const float4 n2 = *reinterpret_cast<const float4*>(&Nf[kbase + 8]);
        const float4 n3 = *reinterpret_cast<const float4*>(&Nf[kbase + 12]);
        const float nk[16] = {n0.x, n0.y, n0.z, n0.w, n1.x, n1.y, n1.z, n1.w,
                              n2.x, n2.y, n2.z, n2.w, n3.x, n3.y, n3.z, n3.w};
#pragma unroll
        for (int j = 0; j < 16; ++j) {
            const int k = kbase + j;
#pragma unroll
            for (int i = 0; i < 16; ++i) {
                const float v = __fadd_rn(__fsub_rn(Ai[i], acc[i][j]), nk[j]);
                if (v < best[i]) { best[i] = v; bidx[i] = k; }
            }
        }
    }
    __syncthreads();   // all le/z2 reads done; overlay reduction buffer
#pragma unroll
    for (int i = 0; i < 16; ++i) {
        const int px = ((i >> 2) * 16 + tp) * 4 + (i & 3);
        const unsigned u   = __float_as_uint(best[i]);
        const unsigned key = (u & 0x80000000u) ? ~u : (u | 0x80000000u);
        red[px * 17 + tk] = ((unsigned long long)key << 32) | (unsigned)bidx[i];
    }
    __syncthreads();
    {
        unsigned long long bv = ~0ULL;
#pragma unroll 4
        for (int q2 = 0; q2 < 16; ++q2) {
            const unsigned long long v = red[t * 17 + q2];
            bv = (v < bv) ? v : bv;
        }
        atomicMin(&amin[pix0 + t], bv);
    }
}

// ---------------------------------------------------------------- unpack argmin
__global__ __launch_bounds__(256) void k_combine(const unsigned long long* __restrict__ amin,
                                                 float* __restrict__ out_ind) {
    const int n = blockIdx.x * 256 + threadIdx.x;
    out_ind[n] = (float)(unsigned)(amin[n] & 0xFFFFFFFFull);
}

// ---------------------------------------------------------------- gather z_q (overwrite z_e) + partial MSE (f64)
__global__ __launch_bounds__(256) void k_gather(const float* __restrict__ embed,
                                                float* __restrict__ out,
                                                const float* __restrict__ out_ind,
                                                float* __restrict__ part) {
    __shared__ double wsum[4];
    const int t = threadIdx.x;
    const int g = t >> 5, l = t & 31;
    const int n = blockIdx.x * 8 + g;
    const int idx = (int)(out_ind[n] + 0.5f);
    const float4* ev4 = reinterpret_cast<const float4*>(embed + (size_t)idx * EDIM);
    float4* zp = reinterpret_cast<float4*>(out + (size_t)n * EDIM);
    double s = 0.0;
#pragma unroll
    for (int r = 0; r < 2; ++r) {
        const float4 ev = ev4[l + r * 32];
        const float4 zv = zp[l + r * 32];
        const double dx = (double)ev.x - zv.x, dy = (double)ev.y - zv.y;
        const double dz = (double)ev.z - zv.z, dw = (double)ev.w - zv.w;
        s += dx * dx + dy * dy + dz * dz + dw * dw;
        zp[l + r * 32] = ev;             // z_q_st == z_q numerically
    }
    for (int off = 32; off; off >>= 1) s += __shfl_down(s, off, 64);
    const int wid = t >> 6, lane = t & 63;
    if (lane == 0) wsum[wid] = s;
    __syncthreads();
    if (t == 0) part[blockIdx.x] = (float)(wsum[0] + wsum[1] + wsum[2] + wsum[3]);
}

// ---------------------------------------------------------------- final diff reduction (f64)
__global__ __launch_bounds__(256) void k_final(const float* __restrict__ part,
                                               float* __restrict__ out_diff) {
    __shared__ double wsum[4];
    double s = 0.0;
#pragma unroll
    for (int i = 0; i < 4; ++i) s += (double)part[threadIdx.x + i * 256];
    for (int off = 32; off; off >>= 1) s += __shfl_down(s, off, 64);
    const int wid = threadIdx.x >> 6, lane = threadIdx.x & 63;
    if (lane == 0) wsum[wid] = s;
    __syncthreads();
    if (threadIdx.x == 0)
        out_diff[0] = (float)(2.0 * (wsum[0] + wsum[1] + wsum[2] + wsum[3]) / 2097152.0);
}

extern "C" void kernel_launch(void* const* d_in, const int* in_sizes, int n_in,
                              void* d_out, int out_size, void* d_ws, size_t ws_size,
                              hipStream_t stream) {
    const float* z     = (const float*)d_in[0];
    const float* pw    = (const float*)d_in[1];
    const float* pb    = (const float*)d_in[2];
    const float* embed = (const float*)d_in[3];
    float* out = (float*)d_out;
    char*  ws  = (char*)d_ws;

    unsigned long long* amin = (unsigned long long*)(ws + WS_AMIN);
    float*              A    = (float*)(ws + WS_A);
    float*              Nf   = (float*)(ws + WS_N);
    float*              part = (float*)(ws + WS_PART);

    float* ze       = out + OUT_ZQ;      // z_e lives in z_q slot, overwritten by gather
    float* out_diff = out + OUT_DIFF;
    float* out_ind  = out + OUT_IND;

    k_init    <<<32,   256, 0, stream>>>(amin);
    k_ze_np   <<<512,  256, 0, stream>>>(z, pw, pb, ze);
    k_rowstats<<<64,   256, 0, stream>>>(ze, embed, A, Nf);
    k_dist_np <<<512,  256, 0, stream>>>(ze, embed, A, Nf, amin);
    k_combine <<<32,   256, 0, stream>>>(amin, out_ind);
    k_gather  <<<1024, 256, 0, stream>>>(embed, out + OUT_ZQ, out_ind, part);
    k_final   <<<1,    256, 0, stream>>>(part, out_diff);
}

// Round 10
// 426.763 us; speedup vs baseline: 4.8504x; 1.4708x over previous
//
#include <hip/hip_runtime.h>

// Problem constants
#define NPIX 8192      // B*H*W
#define EDIM 256
#define KCB  8192
#define OUT_ZQ   0
#define OUT_DIFF 2097152
#define OUT_IND  2097153

// ws layout (bytes) — total 135,168 <= proven 565,248
#define WS_AMIN 0          // 8192 u64 packed (key<<32 | idx)
#define WS_A    65536      // 8192 f32
#define WS_N    98304      // 8192 f32
#define WS_PART 131072     // 1024 f32

// ---------------------------------------------------------------- init packed argmin array
__global__ __launch_bounds__(256) void k_init(unsigned long long* __restrict__ amin) {
    amin[blockIdx.x * 256 + threadIdx.x] = ~0ULL;
}

// ---------------------------------------------------------------- z_e: bit-exact np.einsum replica
__global__ __launch_bounds__(256) void k_ze_np(const float* __restrict__ z,
                                               const float* __restrict__ pw,
                                               const float* __restrict__ pb,
                                               float* __restrict__ ze) {
    __shared__ float lz[32][16];
    __shared__ float lw[256][33];
    const int t   = threadIdx.x;
    const int b   = blockIdx.x >> 6;
    const int hw0 = (blockIdx.x & 63) * 16;

    float acc[16];
#pragma unroll
    for (int p = 0; p < 16; ++p) acc[p] = 0.0f;

    for (int cc = 0; cc < 256; cc += 32) {
        float4 wv[8];
        const float4* wsrc = reinterpret_cast<const float4*>(pw + (size_t)t * 256 + cc);
#pragma unroll
        for (int i = 0; i < 8; ++i) wv[i] = wsrc[i];
        float zv[2];
#pragma unroll
        for (int i = 0; i < 2; ++i) {
            const int f = t + i * 256;           // 0..511
            zv[i] = z[(size_t)(b * 256 + cc + (f >> 4)) * 1024 + hw0 + (f & 15)];
        }
        __syncthreads();   // previous chunk's reads complete
#pragma unroll
        for (int i = 0; i < 8; ++i) {
            lw[t][i * 4 + 0] = wv[i].x;
            lw[t][i * 4 + 1] = wv[i].y;
            lw[t][i * 4 + 2] = wv[i].z;
            lw[t][i * 4 + 3] = wv[i].w;
        }
#pragma unroll
        for (int i = 0; i < 2; ++i) {
            const int f = t + i * 256;
            lz[f >> 4][f & 15] = zv[i];
        }
        __syncthreads();
#pragma unroll 8
        for (int cl = 0; cl < 32; ++cl) {
            const float wl = lw[t][cl];
#pragma unroll
            for (int p = 0; p < 16; ++p)
                acc[p] = __fadd_rn(acc[p], __fmul_rn(lz[cl][p], wl));
        }
    }
    const float bb = pb[t];
#pragma unroll
    for (int p = 0; p < 16; ++p)
        ze[(size_t)(b * 1024 + hw0 + p) * 256 + t] = __fadd_rn(acc[p], bb);
}

// ---------------------------------------------------------------- np.sum(x*x, axis=1) pairwise replica (n=256)
__global__ __launch_bounds__(256) void k_rowstats(const float* __restrict__ ze,
                                                  const float* __restrict__ embed,
                                                  float* __restrict__ A,
                                                  float* __restrict__ Nf) {
    const int gid = blockIdx.x * 256 + threadIdx.x;     // 0..16383
    const float* row = (gid < 8192) ? (ze + (size_t)gid * 256)
                                    : (embed + (size_t)(gid - 8192) * 256);
    float blk[2];
#pragma unroll
    for (int half = 0; half < 2; ++half) {
        const float4* r4 = reinterpret_cast<const float4*>(row + half * 128);
        float r[8];
#pragma unroll
        for (int i = 0; i < 16; ++i) {
            const float4 a = r4[i * 2], b = r4[i * 2 + 1];
            const float s[8] = {__fmul_rn(a.x, a.x), __fmul_rn(a.y, a.y),
                                __fmul_rn(a.z, a.z), __fmul_rn(a.w, a.w),
                                __fmul_rn(b.x, b.x), __fmul_rn(b.y, b.y),
                                __fmul_rn(b.z, b.z), __fmul_rn(b.w, b.w)};
            if (i == 0) {
#pragma unroll
                for (int j = 0; j < 8; ++j) r[j] = s[j];
            } else {
#pragma unroll
                for (int j = 0; j < 8; ++j) r[j] = __fadd_rn(r[j], s[j]);
            }
        }
        blk[half] = __fadd_rn(__fadd_rn(__fadd_rn(r[0], r[1]), __fadd_rn(r[2], r[3])),
                              __fadd_rn(__fadd_rn(r[4], r[5]), __fadd_rn(r[6], r[7])));
    }
    const float res = __fadd_rn(blk[0], blk[1]);
    if (gid < 8192) A[gid] = res;
    else            Nf[gid - 8192] = res;
}

// ---------------------------------------------------------------- dist replica + argmin, 16px x 8k register tile
// grid 1024 = 32 px-tiles(256 px) x 32 k-splits(256 k). 256 thr = 16 tp x 16 tk.
// thread: 16 px (px = (q*16+tp)*4+m) x 8 k (k = k0+kc+tk*8+j). kc chunks of 128 k, cc passes of 32 c.
// LDS 48 KB: le[c32][k128] 16KB + z2[c32][px256] 32KB (2*z_e, exact prescale). 2 blocks/CU.
// Per c: 4 z-b128 + 2 e-b128 per 128 wave-FMA -> LDS ~=89% of VALU -> near balance.
// Chain per (px,k): c-ascending single fmaf on 2*z_e — bit-identical to rounds 5-7.
// Cross-block argmin: packed u64 atomicMin (order-preserving key<<32 | k) — np first-occurrence ties.
__global__ __launch_bounds__(256, 2) void k_dist_np(const float* __restrict__ ze,
                                                    const float* __restrict__ embed,
                                                    const float* __restrict__ A,
                                                    const float* __restrict__ Nf,
                                                    unsigned long long* __restrict__ amin) {
    __shared__ __align__(16) char smem[49152];
    float (*le)[128] = reinterpret_cast<float (*)[128]>(smem);            // [c32][k128] 16 KB
    float (*z2)[256] = reinterpret_cast<float (*)[256]>(smem + 16384);    // [c32][px256] 32 KB
    unsigned long long* red = reinterpret_cast<unsigned long long*>(smem); // overlay [256][17] 34.8 KB

    const int t    = threadIdx.x;
    const int ks   = blockIdx.x & 31;
    const int pt   = blockIdx.x >> 5;
    const int pix0 = pt * 256;
    const int k0   = ks * 256;
    const int tp   = t & 15, tk = t >> 4;
    const int er   = t >> 1, eh = (t & 1) * 16;   // e staging coords

    float best[16];
    int   bidx[16];
#pragma unroll
    for (int i = 0; i < 16; ++i) { best[i] = 3.402823466e+38f; bidx[i] = 0x7fffffff; }

    float Ai[16];
#pragma unroll
    for (int q = 0; q < 4; ++q)
#pragma unroll
        for (int m = 0; m < 4; ++m)
            Ai[q * 4 + m] = A[pix0 + (q * 16 + tp) * 4 + m];

    for (int kc = 0; kc < 256; kc += 128) {
        float acc[16][8];
#pragma unroll
        for (int i = 0; i < 16; ++i)
#pragma unroll
            for (int j = 0; j < 8; ++j) acc[i][j] = 0.0f;

        const int kbase = k0 + kc + tk * 8;

        for (int cc = 0; cc < 256; cc += 32) {
            // prefetch: embed row k0+kc+er (16 c at eh) and ze row pix0+t (32 c)
            float4 se[4], sz[8];
            const float4* esrc = reinterpret_cast<const float4*>(
                embed + (size_t)(k0 + kc + er) * 256 + cc + eh);
#pragma unroll
            for (int m = 0; m < 4; ++m) se[m] = esrc[m];
            const float4* zsrc = reinterpret_cast<const float4*>(
                ze + (size_t)(pix0 + t) * 256 + cc);
#pragma unroll
            for (int m = 0; m < 8; ++m) sz[m] = zsrc[m];
            __syncthreads();   // prior inner-loop reads complete
#pragma unroll
            for (int m = 0; m < 4; ++m) {
                le[eh + m * 4 + 0][er] = se[m].x;
                le[eh + m * 4 + 1][er] = se[m].y;
                le[eh + m * 4 + 2][er] = se[m].z;
                le[eh + m * 4 + 3][er] = se[m].w;
            }
#pragma unroll
            for (int m = 0; m < 8; ++m) {
                z2[m * 4 + 0][t] = __fmul_rn(2.0f, sz[m].x);   // exact prescale
                z2[m * 4 + 1][t] = __fmul_rn(2.0f, sz[m].y);
                z2[m * 4 + 2][t] = __fmul_rn(2.0f, sz[m].z);
                z2[m * 4 + 3][t] = __fmul_rn(2.0f, sz[m].w);
            }
            __syncthreads();
#pragma unroll 2
            for (int c = 0; c < 32; ++c) {
                const float4 e0 = *reinterpret_cast<const float4*>(&le[c][tk * 8]);
                const float4 e1 = *reinterpret_cast<const float4*>(&le[c][tk * 8 + 4]);
                float4 zq[4];
#pragma unroll
                for (int q = 0; q < 4; ++q)
                    zq[q] = *reinterpret_cast<const float4*>(&z2[c][(q * 16 + tp) * 4]);
#define FMA8(i, zv)                                          \
    acc[i][0] = fmaf(zv, e0.x, acc[i][0]);                   \
    acc[i][1] = fmaf(zv, e0.y, acc[i][1]);                   \
    acc[i][2] = fmaf(zv, e0.z, acc[i][2]);                   \
    acc[i][3] = fmaf(zv, e0.w, acc[i][3]);                   \
    acc[i][4] = fmaf(zv, e1.x, acc[i][4]);                   \
    acc[i][5] = fmaf(zv, e1.y, acc[i][5]);                   \
    acc[i][6] = fmaf(zv, e1.z, acc[i][6]);                   \
    acc[i][7] = fmaf(zv, e1.w, acc[i][7]);
#pragma unroll
                for (int q = 0; q < 4; ++q) {
                    FMA8(q * 4 + 0, zq[q].x)
                    FMA8(q * 4 + 1, zq[q].y)
                    FMA8(q * 4 + 2, zq[q].z)
                    FMA8(q * 4 + 3, zq[q].w)
                }
#undef FMA8
            }
        }
        // scores; thread-local k ascending (kc asc, j asc) -> strict < keeps first occurrence
        const float4 n0 = *reinterpret_cast<const float4*>(&Nf[kbase]);
        const float4 n1 = *reinterpret_cast<const float4*>(&Nf[kbase + 4]);
        const float nk[8] = {n0.x, n0.y, n0.z, n0.w, n1.x, n1.y, n1.z, n1.w};
#pragma unroll
        for (int j = 0; j < 8; ++j) {
            const int k = kbase + j;
#pragma unroll
            for (int i = 0; i < 16; ++i) {
                const float v = __fadd_rn(__fsub_rn(Ai[i], acc[i][j]), nk[j]);
                if (v < best[i]) { best[i] = v; bidx[i] = k; }
            }
        }
    }
    __syncthreads();   // all le/z2 reads done; overlay reduction buffer
#pragma unroll
    for (int i = 0; i < 16; ++i) {
        const int px = ((i >> 2) * 16 + tp) * 4 + (i & 3);
        const unsigned u   = __float_as_uint(best[i]);
        const unsigned key = (u & 0x80000000u) ? ~u : (u | 0x80000000u);
        red[px * 17 + tk] = ((unsigned long long)key << 32) | (unsigned)bidx[i];
    }
    __syncthreads();
    {
        unsigned long long bv = ~0ULL;
#pragma unroll 4
        for (int q2 = 0; q2 < 16; ++q2) {   // tk ascending; packed min == lexicographic (v, k)
            const unsigned long long v = red[t * 17 + q2];
            bv = (v < bv) ? v : bv;
        }
        atomicMin(&amin[pix0 + t], bv);
    }
}

// ---------------------------------------------------------------- unpack argmin
__global__ __launch_bounds__(256) void k_combine(const unsigned long long* __restrict__ amin,
                                                 float* __restrict__ out_ind) {
    const int n = blockIdx.x * 256 + threadIdx.x;
    out_ind[n] = (float)(unsigned)(amin[n] & 0xFFFFFFFFull);
}

// ---------------------------------------------------------------- gather z_q (overwrite z_e) + partial MSE (f64)
__global__ __launch_bounds__(256) void k_gather(const float* __restrict__ embed,
                                                float* __restrict__ out,
                                                const float* __restrict__ out_ind,
                                                float* __restrict__ part) {
    __shared__ double wsum[4];
    const int t = threadIdx.x;
    const int g = t >> 5, l = t & 31;
    const int n = blockIdx.x * 8 + g;
    const int idx = (int)(out_ind[n] + 0.5f);
    const float4* ev4 = reinterpret_cast<const float4*>(embed + (size_t)idx * EDIM);
    float4* zp = reinterpret_cast<float4*>(out + (size_t)n * EDIM);
    double s = 0.0;
#pragma unroll
    for (int r = 0; r < 2; ++r) {
        const float4 ev = ev4[l + r * 32];
        const float4 zv = zp[l + r * 32];
        const double dx = (double)ev.x - zv.x, dy = (double)ev.y - zv.y;
        const double dz = (double)ev.z - zv.z, dw = (double)ev.w - zv.w;
        s += dx * dx + dy * dy + dz * dz + dw * dw;
        zp[l + r * 32] = ev;             // z_q_st == z_q numerically
    }
    for (int off = 32; off; off >>= 1) s += __shfl_down(s, off, 64);
    const int wid = t >> 6, lane = t & 63;
    if (lane == 0) wsum[wid] = s;
    __syncthreads();
    if (t == 0) part[blockIdx.x] = (float)(wsum[0] + wsum[1] + wsum[2] + wsum[3]);
}

// ---------------------------------------------------------------- final diff reduction (f64)
__global__ __launch_bounds__(256) void k_final(const float* __restrict__ part,
                                               float* __restrict__ out_diff) {
    __shared__ double wsum[4];
    double s = 0.0;
#pragma unroll
    for (int i = 0; i < 4; ++i) s += (double)part[threadIdx.x + i * 256];
    for (int off = 32; off; off >>= 1) s += __shfl_down(s, off, 64);
    const int wid = threadIdx.x >> 6, lane = threadIdx.x & 63;
    if (lane == 0) wsum[wid] = s;
    __syncthreads();
    if (threadIdx.x == 0)
        out_diff[0] = (float)(2.0 * (wsum[0] + wsum[1] + wsum[2] + wsum[3]) / 2097152.0);
}

extern "C" void kernel_launch(void* const* d_in, const int* in_sizes, int n_in,
                              void* d_out, int out_size, void* d_ws, size_t ws_size,
                              hipStream_t stream) {
    const float* z     = (const float*)d_in[0];
    const float* pw    = (const float*)d_in[1];
    const float* pb    = (const float*)d_in[2];
    const float* embed = (const float*)d_in[3];
    float* out = (float*)d_out;
    char*  ws  = (char*)d_ws;

    unsigned long long* amin = (unsigned long long*)(ws + WS_AMIN);
    float*              A    = (float*)(ws + WS_A);
    float*              Nf   = (float*)(ws + WS_N);
    float*              part = (float*)(ws + WS_PART);

    float* ze       = out + OUT_ZQ;      // z_e lives in z_q slot, overwritten by gather
    float* out_diff = out + OUT_DIFF;
    float* out_ind  = out + OUT_IND;

    k_init    <<<32,   256, 0, stream>>>(amin);
    k_ze_np   <<<512,  256, 0, stream>>>(z, pw, pb, ze);
    k_rowstats<<<64,   256, 0, stream>>>(ze, embed, A, Nf);
    k_dist_np <<<1024, 256, 0, stream>>>(ze, embed, A, Nf, amin);
    k_combine <<<32,   256, 0, stream>>>(amin, out_ind);
    k_gather  <<<1024, 256, 0, stream>>>(embed, out + OUT_ZQ, out_ind, part);
    k_final   <<<1,    256, 0, stream>>>(part, out_diff);
}